// Round 1
// baseline (289.487 us; speedup 1.0000x reference)
//
#include <hip/hip_runtime.h>
#include <hip/hip_bf16.h>

#define NUM_FIELDS 39
#define PER_FIELD_VOCAB 10000
#define EMBED_DIM 128
#define KPAD 48          // F padded to 48 for three K=16 chunks (32x32x16 MFMA)
#define NL 5             // 2 (W0) + 3 (W1) interaction slabs
#define RANK 128
#define BATCH 2048
#define LDE 56           // eT row stride in bf16 elems: 48 + 8 pad -> 112 B, 16B-aligned

typedef __bf16  bf16x8  __attribute__((ext_vector_type(8)));
typedef __bf16  bf16x4  __attribute__((ext_vector_type(4)));
typedef float   f32x16  __attribute__((ext_vector_type(16)));

// ---------------------------------------------------------------------------
// Precompute: W0 [2,128,39] f32, W1 [3,128,39] f32  ->  Wb [5][128][48] bf16
// (zero-padded in f; re-run every launch since d_ws is re-poisoned)
// ---------------------------------------------------------------------------
__global__ __launch_bounds__(256) void prep_w(const float* __restrict__ W0,
                                              const float* __restrict__ W1,
                                              __bf16* __restrict__ Wb) {
    int i = blockIdx.x * 256 + threadIdx.x;       // 5*128*48 = 30720 total
    if (i >= NL * RANK * KPAD) return;
    int f  = i % KPAD;
    int rl = i / KPAD;
    int r  = rl & (RANK - 1);
    int l  = rl >> 7;
    float v = 0.f;
    if (f < NUM_FIELDS) {
        if (l < 2) v = W0[(l * RANK + r) * NUM_FIELDS + f];
        else       v = W1[((l - 2) * RANK + r) * NUM_FIELDS + f];
    }
    Wb[i] = (__bf16)v;
}

// ---------------------------------------------------------------------------
// Main: one workgroup (256 thr = 4 waves) per batch element.
//   ret[b] = bias + sum_f linear[idx] + sum_{r,d} dp0*dp1 + sum_{r,d} dp2*dp3*dp4
//   dp_l[r,d] = sum_f W[l,r,f] * emb[b,f,d]   via mfma_f32_32x32x16_bf16, K=48
// Wave w owns r-tile [32w,32w+32); loops over 4 d-tiles of 32.
// Correctness note: we only need the sum over k and the sum over all (r,d),
// so any consistent per-lane k-order for A and B and any C/D layout is valid.
// ---------------------------------------------------------------------------
__global__ __launch_bounds__(256) void tfm_main(const int* __restrict__ x,
                                                const float* __restrict__ embed_table,
                                                const float* __restrict__ linear_table,
                                                const float* __restrict__ bias,
                                                const __bf16* __restrict__ Wb,
                                                float* __restrict__ out,
                                                int out_size) {
    __shared__ int   sidx[NUM_FIELDS];
    __shared__ __align__(16) __bf16 eT[EMBED_DIM * LDE];   // eT[d][f], 14336 B
    __shared__ float wpart[4];

    const int tid  = threadIdx.x;
    const int b    = blockIdx.x;
    const int wave = tid >> 6, lane = tid & 63;
    const int ln   = lane & 31, hw = lane >> 5;

    if (tid < NUM_FIELDS)
        sidx[tid] = x[b * NUM_FIELDS + tid] + tid * PER_FIELD_VOCAB;
    __syncthreads();

    // A-fragments for this wave's 32 r's: issued before the gather so the
    // L2-broadcast latency hides under it. 15 x b128 = 60 VGPR.
    const int rr = wave * 32 + ln;
    bf16x8 af[NL][3];
#pragma unroll
    for (int l = 0; l < NL; ++l)
#pragma unroll
        for (int kc = 0; kc < 3; ++kc)
            af[l][kc] = *reinterpret_cast<const bf16x8*>(
                &Wb[(size_t)(l * RANK + rr) * KPAD + kc * 16 + hw * 8]);

    // Linear term folded into the per-thread partial before the block reduce.
    float partial = (tid < NUM_FIELDS) ? linear_table[sidx[tid]] : 0.f;

    // Gather -> LDS transpose. Unit u = (f4, d): 4 coalesced dword loads
    // (4 rows, same column d), pack 4 consecutive-f bf16, one 8B LDS write.
    // 12 f4-groups x 128 d = 1536 units = exactly 6 iters of 256 threads.
    // f4 is wave-uniform (128 units per group). f>=39 writes zeros (K-pad).
#pragma unroll
    for (int it = 0; it < 6; ++it) {
        int u  = it * 256 + tid;
        int f4 = u >> 7;
        int d  = u & (EMBED_DIM - 1);
        int f  = f4 * 4;
        float v0 = 0.f, v1 = 0.f, v2 = 0.f, v3 = 0.f;
        if (f + 0 < NUM_FIELDS) v0 = embed_table[(long)sidx[f + 0] * EMBED_DIM + d];
        if (f + 1 < NUM_FIELDS) v1 = embed_table[(long)sidx[f + 1] * EMBED_DIM + d];
        if (f + 2 < NUM_FIELDS) v2 = embed_table[(long)sidx[f + 2] * EMBED_DIM + d];
        if (f + 3 < NUM_FIELDS) v3 = embed_table[(long)sidx[f + 3] * EMBED_DIM + d];
        bf16x4 pk = {(__bf16)v0, (__bf16)v1, (__bf16)v2, (__bf16)v3};
        *reinterpret_cast<bf16x4*>(&eT[d * LDE + f4 * 4]) = pk;
    }
    __syncthreads();

    f32x16 zacc;
#pragma unroll
    for (int i = 0; i < 16; ++i) zacc[i] = 0.f;
    f32x16 psum = zacc;

#pragma unroll
    for (int dt = 0; dt < 4; ++dt) {
        const __bf16* ep = &eT[(dt * 32 + ln) * LDE + hw * 8];
        bf16x8 bf0 = *reinterpret_cast<const bf16x8*>(ep);
        bf16x8 bf1 = *reinterpret_cast<const bf16x8*>(ep + 16);
        bf16x8 bf2 = *reinterpret_cast<const bf16x8*>(ep + 32);

        f32x16 a0 = __builtin_amdgcn_mfma_f32_32x32x16_bf16(af[0][0], bf0, zacc, 0, 0, 0);
        a0 = __builtin_amdgcn_mfma_f32_32x32x16_bf16(af[0][1], bf1, a0, 0, 0, 0);
        a0 = __builtin_amdgcn_mfma_f32_32x32x16_bf16(af[0][2], bf2, a0, 0, 0, 0);
        f32x16 a1 = __builtin_amdgcn_mfma_f32_32x32x16_bf16(af[1][0], bf0, zacc, 0, 0, 0);
        a1 = __builtin_amdgcn_mfma_f32_32x32x16_bf16(af[1][1], bf1, a1, 0, 0, 0);
        a1 = __builtin_amdgcn_mfma_f32_32x32x16_bf16(af[1][2], bf2, a1, 0, 0, 0);
        f32x16 b0 = __builtin_amdgcn_mfma_f32_32x32x16_bf16(af[2][0], bf0, zacc, 0, 0, 0);
        b0 = __builtin_amdgcn_mfma_f32_32x32x16_bf16(af[2][1], bf1, b0, 0, 0, 0);
        b0 = __builtin_amdgcn_mfma_f32_32x32x16_bf16(af[2][2], bf2, b0, 0, 0, 0);
        f32x16 b1 = __builtin_amdgcn_mfma_f32_32x32x16_bf16(af[3][0], bf0, zacc, 0, 0, 0);
        b1 = __builtin_amdgcn_mfma_f32_32x32x16_bf16(af[3][1], bf1, b1, 0, 0, 0);
        b1 = __builtin_amdgcn_mfma_f32_32x32x16_bf16(af[3][2], bf2, b1, 0, 0, 0);
        f32x16 b2 = __builtin_amdgcn_mfma_f32_32x32x16_bf16(af[4][0], bf0, zacc, 0, 0, 0);
        b2 = __builtin_amdgcn_mfma_f32_32x32x16_bf16(af[4][1], bf1, b2, 0, 0, 0);
        b2 = __builtin_amdgcn_mfma_f32_32x32x16_bf16(af[4][2], bf2, b2, 0, 0, 0);

        // dp0*dp1 + dp2*dp3*dp4 elementwise; 16 independent fmac lanes, no chain.
        psum += a0 * a1;
        psum += b0 * b1 * b2;
    }

#pragma unroll
    for (int i = 0; i < 16; ++i) partial += psum[i];

    // Block reduction: wave shuffle -> LDS -> thread 0.
#pragma unroll
    for (int off = 32; off > 0; off >>= 1)
        partial += __shfl_down(partial, off, 64);
    if (lane == 0) wpart[wave] = partial;
    __syncthreads();
    if (tid == 0)
        out[b] = wpart[0] + wpart[1] + wpart[2] + wpart[3] + bias[0];

    // Second tuple output ("0") and any trailing pad.
    if (b == 0)
        for (int j = BATCH + tid; j < out_size; j += 256)
            out[j] = 0.f;
}

extern "C" void kernel_launch(void* const* d_in, const int* in_sizes, int n_in,
                              void* d_out, int out_size, void* d_ws, size_t ws_size,
                              hipStream_t stream) {
    const int*   x            = (const int*)d_in[0];
    const float* embed_table  = (const float*)d_in[1];
    const float* linear_table = (const float*)d_in[2];
    const float* bias         = (const float*)d_in[3];
    const float* W0           = (const float*)d_in[4];
    const float* W1           = (const float*)d_in[5];
    __bf16*      Wb           = (__bf16*)d_ws;   // 30720 * 2 B = 60 KB scratch

    prep_w<<<(NL * RANK * KPAD + 255) / 256, 256, 0, stream>>>(W0, W1, Wb);
    tfm_main<<<BATCH, 256, 0, stream>>>(x, embed_table, linear_table, bias, Wb,
                                        (float*)d_out, out_size);
}

// Round 2
// 287.322 us; speedup vs baseline: 1.0075x; 1.0075x over previous
//
#include <hip/hip_runtime.h>
#include <hip/hip_bf16.h>

#define NUM_FIELDS 39
#define PER_FIELD_VOCAB 10000
#define EMBED_DIM 128
#define KPAD 64          // F padded to 64: two K=32 chunks for mfma_f32_16x16x32_bf16
#define NL 5             // 2 (W0) + 3 (W1) interaction slabs
#define RANK 128
#define BATCH 2048

typedef __bf16  bf16x8  __attribute__((ext_vector_type(8)));
typedef float   f32x4   __attribute__((ext_vector_type(4)));

// ---------------------------------------------------------------------------
// Precompute: W0 [2,128,39] f32, W1 [3,128,39] f32  ->  Wb [5][128][64] bf16
// (zero-padded in f; re-run every launch since d_ws is re-poisoned)
// ---------------------------------------------------------------------------
__global__ __launch_bounds__(256) void prep_w(const float* __restrict__ W0,
                                              const float* __restrict__ W1,
                                              __bf16* __restrict__ Wb) {
    int i = blockIdx.x * 256 + threadIdx.x;       // 5*128*64 = 40960 total
    if (i >= NL * RANK * KPAD) return;
    int f = i & (KPAD - 1);
    int r = (i >> 6) & (RANK - 1);
    int l = i >> 13;
    float v = 0.f;
    if (f < NUM_FIELDS) {
        if (l < 2) v = W0[(l * RANK + r) * NUM_FIELDS + f];
        else       v = W1[((l - 2) * RANK + r) * NUM_FIELDS + f];
    }
    Wb[i] = (__bf16)v;
}

// ---------------------------------------------------------------------------
// Main: one workgroup (512 thr = 8 waves) per batch element.
//   ret[b] = bias + sum_f linear[idx] + sum_{r,d} dp0*dp1 + sum_{r,d} dp2*dp3*dp4
//   dp_l[r,d] = sum_f W[l,r,f] * emb[b,f,d]   via mfma_f32_16x16x32_bf16, K=64
// Wave w owns r-tile [16w, 16w+16); loops over 8 d-tiles of 16.
// eT is the transposed embedding tile eT[d][f] bf16, stride 64 elems (128 B),
// XOR-swizzled: byte = d*128 + (col_byte ^ ((d&7)<<4)). Same formula on write
// and read sides (both-sides-or-neither rule), bijective since stride is a
// multiple of 128 B.
// Correctness: only sum over k and sum over all (r,d) are needed, and all 5
// accs share one C/D layout with identical (r,d) element pairing, so the
// product fold is layout-agnostic.
// ---------------------------------------------------------------------------
__global__ __launch_bounds__(512) void tfm_main(const int* __restrict__ x,
                                                const float* __restrict__ embed_table,
                                                const float* __restrict__ linear_table,
                                                const float* __restrict__ bias,
                                                const __bf16* __restrict__ Wb,
                                                float* __restrict__ out,
                                                int out_size) {
    __shared__ int   sidx[NUM_FIELDS];
    __shared__ __align__(16) __bf16 eT[EMBED_DIM * KPAD];   // 16 KB, swizzled
    __shared__ float wpart[8];

    const int tid = threadIdx.x;
    const int b   = blockIdx.x;

    if (tid < NUM_FIELDS)
        sidx[tid] = x[b * NUM_FIELDS + tid] + tid * PER_FIELD_VOCAB;
    __syncthreads();

    // Linear term folded into the per-thread partial before the block reduce.
    float partial = (tid < NUM_FIELDS) ? linear_table[sidx[tid]] : 0.f;

    // Gather -> LDS transpose. Unit u = (f8, d): up to 8 coalesced dword loads
    // (8 field rows, same column d), packed to one b128 LDS write.
    // 8 f8-groups x 128 d = 1024 units = exactly 2 iters of 512 threads.
    // f8 is wave-uniform -> bounds masks are scalar branches; f>=39 groups
    // write pure zeros, which also zero-fills the K-pad (no separate pad loop).
    char* eTb = (char*)eT;
#pragma unroll
    for (int it = 0; it < 2; ++it) {
        int u  = it * 512 + tid;
        int f8 = u >> 7;                 // 0..7, wave-uniform
        int d  = u & (EMBED_DIM - 1);    // per-lane, consecutive -> coalesced
        float v[8];
#pragma unroll
        for (int j = 0; j < 8; ++j) {
            int f = f8 * 8 + j;
            v[j] = (f < NUM_FIELDS) ? embed_table[(long)sidx[f] * EMBED_DIM + d]
                                    : 0.f;
        }
        bf16x8 pk;
#pragma unroll
        for (int j = 0; j < 8; ++j) pk[j] = (__bf16)v[j];
        int off = d * 128 + ((f8 * 16) ^ ((d & 7) << 4));   // byte offset, 16B-aligned
        *reinterpret_cast<bf16x8*>(eTb + off) = pk;
    }
    __syncthreads();

    const int wave = tid >> 6, lane = tid & 63;
    const int m = lane & 15, quad = lane >> 4;   // MFMA A/B fragment lane coords
    const int r0 = wave * 16;                    // this wave's r-tile

    // A-fragments: 10 x b128 from Wb (L2-hot), 40 VGPR.
    bf16x8 afrag[NL][2];
#pragma unroll
    for (int l = 0; l < NL; ++l)
#pragma unroll
        for (int kc = 0; kc < 2; ++kc)
            afrag[l][kc] = *reinterpret_cast<const bf16x8*>(
                &Wb[(size_t)(l * RANK + r0 + m) * KPAD + kc * 32 + quad * 8]);

    f32x4 psum = {0.f, 0.f, 0.f, 0.f};

    for (int dt = 0; dt < 8; ++dt) {
        const int row = dt * 16 + m;             // B column index = d
        bf16x8 bfrag[2];
#pragma unroll
        for (int kc = 0; kc < 2; ++kc) {
            int off = row * 128 + ((kc * 64 + quad * 16) ^ ((m & 7) << 4));
            bfrag[kc] = *reinterpret_cast<const bf16x8*>(eTb + off);
        }

        f32x4 acc[NL];
#pragma unroll
        for (int l = 0; l < NL; ++l) {
            acc[l] = (f32x4){0.f, 0.f, 0.f, 0.f};
#pragma unroll
            for (int kc = 0; kc < 2; ++kc)
                acc[l] = __builtin_amdgcn_mfma_f32_16x16x32_bf16(
                    afrag[l][kc], bfrag[kc], acc[l], 0, 0, 0);
        }
        // dp0*dp1 (W0 pair) + dp2*dp3*dp4 (W1 triple), elementwise in (r,d).
        psum += acc[0] * acc[1] + acc[2] * acc[3] * acc[4];
    }

    partial += psum[0] + psum[1] + psum[2] + psum[3];

    // Block reduction: wave shuffle -> LDS -> thread 0.
#pragma unroll
    for (int off = 32; off > 0; off >>= 1)
        partial += __shfl_down(partial, off, 64);
    if (lane == 0) wpart[wave] = partial;
    __syncthreads();
    if (tid == 0) {
        float s = bias[0];
#pragma unroll
        for (int w = 0; w < 8; ++w) s += wpart[w];
        out[b] = s;
    }

    // Second tuple output ("0") and any trailing pad.
    if (b == 0)
        for (int j = BATCH + tid; j < out_size; j += 512)
            out[j] = 0.f;
}

extern "C" void kernel_launch(void* const* d_in, const int* in_sizes, int n_in,
                              void* d_out, int out_size, void* d_ws, size_t ws_size,
                              hipStream_t stream) {
    const int*   x            = (const int*)d_in[0];
    const float* embed_table  = (const float*)d_in[1];
    const float* linear_table = (const float*)d_in[2];
    const float* bias         = (const float*)d_in[3];
    const float* W0           = (const float*)d_in[4];
    const float* W1           = (const float*)d_in[5];
    __bf16*      Wb           = (__bf16*)d_ws;   // 40960 * 2 B = 80 KB scratch

    prep_w<<<(NL * RANK * KPAD + 255) / 256, 256, 0, stream>>>(W0, W1, Wb);
    tfm_main<<<BATCH, 512, 0, stream>>>(x, embed_table, linear_table, bias, Wb,
                                        (float*)d_out, out_size);
}